// Round 20
// baseline (148.736 us; speedup 1.0000x reference)
//
#include <hip/hip_runtime.h>
#include <stdint.h>

#define S_LEN 3072
#define DIM   1536
#define NH    12
#define HD    128
#define QKV_N 4608   // 3*DIM

typedef unsigned short u16;
typedef unsigned int   u32;
typedef __bf16 bf16x8 __attribute__((ext_vector_type(8)));
typedef float  f32x4  __attribute__((ext_vector_type(4)));
typedef u16    u16x8  __attribute__((ext_vector_type(8)));
typedef u16    u16x4  __attribute__((ext_vector_type(4)));
typedef u32    u32x4  __attribute__((ext_vector_type(4)));

#define AS1 __attribute__((address_space(1)))
#define AS3 __attribute__((address_space(3)))
#define GLL16(g, l) __builtin_amdgcn_global_load_lds((AS1 void*)(g), (AS3 void*)(l), 16, 0, 0)

__device__ __forceinline__ u16 f2bf(float f) {
  unsigned u = __float_as_uint(f);
  u = (u + 0x7fffu + ((u >> 16) & 1u)) >> 16;   // RNE
  return (u16)u;
}
__device__ __forceinline__ float bf2f(u16 b) {
  return __uint_as_float(((unsigned)b) << 16);
}

// ---------------- fused fp32 -> bf16 convert (3 tensors, one launch) ----------
__global__ __launch_bounds__(256) void cvt_bf16_3(const float* __restrict__ in0, u16* __restrict__ out0, int n0,
                                                  const float* __restrict__ in1, u16* __restrict__ out1, int n1,
                                                  const float* __restrict__ in2, u16* __restrict__ out2, int n2) {
  int total = n0 + n1 + n2;
  int stride = gridDim.x * blockDim.x;
  for (int i = blockIdx.x * blockDim.x + threadIdx.x; i < total; i += stride) {
    const float* src; u16* dst; int j;
    if (i < n0)           { src = in0; dst = out0; j = i; }
    else if (i < n0 + n1) { src = in1; dst = out1; j = i - n0; }
    else                  { src = in2; dst = out2; j = i - n0 - n1; }
    float4 v = ((const float4*)src)[j];
    ushort4 o;
    o.x = f2bf(v.x); o.y = f2bf(v.y); o.z = f2bf(v.z); o.w = f2bf(v.w);
    ((ushort4*)dst)[j] = o;
  }
}

// ======= GEMM1 (QKV) 256x256, BK=32, 64KB LDS (2 blocks/CU) + FUSED epilogue ===
// R2-R4 schedule variants all null at 1 block/CU (128KB LDS): barrier drains had
// no sibling waves to hide under. BK=32 halves LDS -> 2 blocks/CU; phase density
// (16 MFMA / barrier) and the proven 16KB-region addressing are unchanged.
__global__ __launch_bounds__(512, 2) void gemm_qkvf(const u16* __restrict__ A,
                                                    const u16* __restrict__ B,
                                                    const float* __restrict__ bias,
                                                    const float* __restrict__ cosb,
                                                    const float* __restrict__ sinb,
                                                    u16* __restrict__ Qp,
                                                    u16* __restrict__ Kp,
                                                    u16* __restrict__ Vt,
                                                    int M, int N, int K) {
  __shared__ __attribute__((aligned(16))) u16 lds[4 * 8192];  // 64 KiB

  const int t = threadIdx.x;
  const int l = t & 63;
  const int w = t >> 6;          // 0..7
  const int wm = w >> 2;         // 0..1  (128 rows)
  const int wn = w & 3;          // 0..3  (64 cols)
  const int lr = l & 15;
  const int lc = l >> 4;

  const int nbx = N >> 8;
  const int nwg = gridDim.x;
  const int q = nwg >> 3, r = nwg & 7;
  const int xcd = blockIdx.x & 7, rest = blockIdx.x >> 3;
  const int wgid = (xcd < r ? xcd * (q + 1) : r * (q + 1) + (xcd - r) * q) + rest;
  const int m0 = (wgid / nbx) * 256;
  const int n0 = (wgid % nbx) * 256;

  const int nk = K >> 5;   // 48 K-slices of 32

  f32x4 acc[8][4];
  #pragma unroll
  for (int i = 0; i < 8; ++i)
    #pragma unroll
    for (int j = 0; j < 4; ++j) acc[i][j] = f32x4{0.f, 0.f, 0.f, 0.f};

  auto frag2 = [&](const u16* region, int row, int ch) {
    int L = row >> 1;
    int slot = ((ch + ((row & 1) << 2)) ^ L) & 7;
    return *(const bf16x8*)(region + L * 64 + slot * 8);
  };
  // stage one 256x32 matrix slice (A or B) of K-slice kt into [buf][ab]
  auto stage_mat = [&](int buf, int ab, int kt) {
    const u16* base = ab ? B : A;
    const int x0 = ab ? n0 : m0;
    u16* dst = lds + (((buf << 1) | ab) * 8192);
    #pragma unroll
    for (int i = 0; i < 2; ++i) {
      int C = t + i * 512;
      int L = C >> 3, s = C & 7;
      int u = s ^ (L & 7);
      int row = 2 * L + (u >> 2), ch = u & 3;
      const u16* src = base + (size_t)(x0 + row) * K + kt * 32 + ch * 8;
      GLL16(src, dst + C * 8);
    }
  };

  // prologue: slice 0 A+B; drain; barrier
  stage_mat(0, 0, 0); stage_mat(0, 1, 0);
  asm volatile("s_waitcnt vmcnt(0)" ::: "memory");
  __builtin_amdgcn_s_barrier();

  for (int kt = 0; kt < nk; ++kt) {
    const int buf = kt & 1, nbuf = buf ^ 1;
    const bool st = (kt + 1 < nk);
    const u16* Ar = lds + (((buf << 1) | 0) * 8192);
    const u16* Br = lds + (((buf << 1) | 1) * 8192);

    bf16x8 bfrag[4], afr[4];

    // ---- ph0: M-half 0; stage A(kt+1) ----
    #pragma unroll
    for (int ni = 0; ni < 4; ++ni) bfrag[ni] = frag2(Br, wn * 64 + ni * 16 + lr, lc);
    #pragma unroll
    for (int mi = 0; mi < 4; ++mi) afr[mi] = frag2(Ar, wm * 128 + mi * 16 + lr, lc);
    if (st) stage_mat(nbuf, 0, kt + 1);
    __builtin_amdgcn_s_barrier();
    __builtin_amdgcn_s_setprio(1);
    #pragma unroll
    for (int mi = 0; mi < 4; ++mi)
      #pragma unroll
      for (int ni = 0; ni < 4; ++ni)
        acc[mi][ni] = __builtin_amdgcn_mfma_f32_16x16x32_bf16(afr[mi], bfrag[ni],
                                                              acc[mi][ni], 0, 0, 0);
    __builtin_amdgcn_s_setprio(0);
    __builtin_amdgcn_s_barrier();

    // ---- ph1: M-half 1 (B reused); stage B(kt+1); drain t+1 after MFMA ----
    #pragma unroll
    for (int mi = 0; mi < 4; ++mi) afr[mi] = frag2(Ar, wm * 128 + 64 + mi * 16 + lr, lc);
    if (st) stage_mat(nbuf, 1, kt + 1);
    __builtin_amdgcn_s_barrier();
    __builtin_amdgcn_s_setprio(1);
    #pragma unroll
    for (int mi = 0; mi < 4; ++mi)
      #pragma unroll
      for (int ni = 0; ni < 4; ++ni)
        acc[4 + mi][ni] = __builtin_amdgcn_mfma_f32_16x16x32_bf16(afr[mi], bfrag[ni],
                                                                  acc[4 + mi][ni], 0, 0, 0);
    __builtin_amdgcn_s_setprio(0);
    if (st) asm volatile("s_waitcnt vmcnt(0)" ::: "memory");
    __builtin_amdgcn_s_barrier();
  }

  // ---- fused epilogue: two 128-row passes through the 64KB LDS ----
  const int sec = n0 / DIM;           // 0=q, 1=k, 2=v (tile never straddles)
  const int h0 = (n0 % DIM) >> 7;

  float bv[4];
  #pragma unroll
  for (int ni = 0; ni < 4; ++ni)
    bv[ni] = bias[n0 + wn * 64 + ni * 16 + lr];

  #pragma unroll
  for (int p = 0; p < 2; ++p) {
    __syncthreads();
    if (wm == p) {
      #pragma unroll
      for (int mi = 0; mi < 8; ++mi) {
        int rbase = mi * 16 + lc * 4;        // 0..127 within pass
        int s4 = (rbase >> 3) & 15;          // rr<4 never carries into bit 3
        #pragma unroll
        for (int ni = 0; ni < 4; ++ni) {
          int scol = (wn * 64 + ni * 16 + lr) ^ (s4 << 4);
          #pragma unroll
          for (int rr = 0; rr < 4; ++rr)
            lds[(rbase + rr) * 256 + scol] = f2bf(acc[mi][ni][rr] + bv[ni]);
        }
      }
    }
    __syncthreads();

    if (sec < 2) {
      u16* dst = sec ? Kp : Qp;
      const float sc = sec ? 1.f : (0.08838834764831845f * 1.4426950408889634f);
      #pragma unroll
      for (int i = 0; i < 8; ++i) {
        int id = i * 512 + t;                // 4096: 128 rows x 32 c16
        int row = id >> 5, c16 = id & 31;
        int srow = m0 + p * 128 + row;
        int s4 = (row >> 3) & 15;
        int c8 = c16 * 8;
        u16x8 x  = *(const u16x8*)(lds + row * 256 + (c8 ^ (s4 << 4)));
        u16x8 xp = *(const u16x8*)(lds + row * 256 + ((c8 ^ 64) ^ (s4 << 4)));
        int h = h0 + (c8 >> 7);
        int d = c8 & 127;
        float cs[8], sn[8];
        *(float4*)(cs)     = *(const float4*)(cosb + (size_t)srow * HD + d);
        *(float4*)(cs + 4) = *(const float4*)(cosb + (size_t)srow * HD + d + 4);
        *(float4*)(sn)     = *(const float4*)(sinb + (size_t)srow * HD + d);
        *(float4*)(sn + 4) = *(const float4*)(sinb + (size_t)srow * HD + d + 4);
        const float sg = (d & 64) ? 1.f : -1.f;
        u16x8 o;
        #pragma unroll
        for (int j = 0; j < 8; ++j)
          o[j] = f2bf((bf2f(x[j]) * cs[j] + sg * bf2f(xp[j]) * sn[j]) * sc);
        *(u16x8*)(dst + ((size_t)h * S_LEN + srow) * HD + d) = o;
      }
    } else {
      #pragma unroll
      for (int i = 0; i < 8; ++i) {
        int id = i * 512 + t;                // 4096: 256 cols x 16 sch_local
        int col = (((id >> 6) & 31) << 3) | ((id >> 3) & 7);
        int schl = (id & 7) | (((id >> 11) & 1) << 3);
        int h = h0 + (col >> 7), d = col & 127;
        int scol = col ^ ((schl & 15) << 4); // s4 = (row>>3)&15 == schl
        u16x8 v;
        #pragma unroll
        for (int e = 0; e < 8; ++e)
          v[e] = lds[(schl * 8 + e) * 256 + scol];
        *(u16x8*)(Vt + ((size_t)h * HD + d) * S_LEN + m0 + p * 128 + schl * 8) = v;
      }
    }
  }
}

// --------- GEMM2 (proj): 128x128, LDS-staged fp32 epilogue + XCD chunking ------
__device__ __forceinline__ bf16x8 lds_frag(const u16* base, int row, int ch) {
  return *(const bf16x8*)(base + row * 64 + ((ch ^ row) & 7) * 8);
}

__global__ __launch_bounds__(256) void gemm_proj(const u16* __restrict__ A,
                                                 const u16* __restrict__ B,
                                                 float* __restrict__ Cout,
                                                 int M, int N, int K) {
  __shared__ __attribute__((aligned(16))) u16 smem[2 * 128 * 64];  // 32 KiB
  u16* Asm = smem;
  u16* Bsm = smem + 128 * 64;

  const int t = threadIdx.x;
  const int l = t & 63;
  const int w = t >> 6;
  const int wm = w >> 1, wn = w & 1;
  const int lr = l & 15;
  const int lq = l >> 4;

  const int nbx = N >> 7;   // 12
  const int nwg = gridDim.x;
  const int qc = nwg >> 3, rc = nwg & 7;
  const int xcd = blockIdx.x & 7, rest = blockIdx.x >> 3;
  const int wgid = (xcd < rc ? xcd * (qc + 1) : rc * (qc + 1) + (xcd - rc) * qc) + rest;
  const int m0 = (wgid / nbx) * 128;
  const int n0 = (wgid % nbx) * 128;

  f32x4 acc[4][4];
  #pragma unroll
  for (int i = 0; i < 4; ++i)
    #pragma unroll
    for (int j = 0; j < 4; ++j) acc[i][j] = f32x4{0.f, 0.f, 0.f, 0.f};

  for (int k0 = 0; k0 < K; k0 += 64) {
    __syncthreads();
    #pragma unroll
    for (int r4 = 0; r4 < 4; ++r4) {
      int C = t + r4 * 256;
      int row = C >> 3, ch = C & 7;
      int sch = (ch ^ row) & 7;
      GLL16(A + (size_t)(m0 + row) * K + k0 + sch * 8, Asm + (size_t)C * 8);
      GLL16(B + (size_t)(n0 + row) * K + k0 + sch * 8, Bsm + (size_t)C * 8);
    }
    __syncthreads();
    #pragma unroll
    for (int ks = 0; ks < 2; ++ks) {
      bf16x8 af[4], bfr[4];
      #pragma unroll
      for (int mi = 0; mi < 4; ++mi)
        af[mi] = lds_frag(Asm, wm * 64 + mi * 16 + lr, ks * 4 + lq);
      #pragma unroll
      for (int ni = 0; ni < 4; ++ni)
        bfr[ni] = lds_frag(Bsm, wn * 64 + ni * 16 + lr, ks * 4 + lq);
      #pragma unroll
      for (int mi = 0; mi < 4; ++mi)
        #pragma unroll
        for (int ni = 0; ni < 4; ++ni)
          acc[mi][ni] = __builtin_amdgcn_mfma_f32_16x16x32_bf16(af[mi], bfr[ni],
                                                                acc[mi][ni], 0, 0, 0);
    }
  }

  float* Cf = (float*)smem;
  #pragma unroll
  for (int p = 0; p < 2; ++p) {
    __syncthreads();
    if (wm == p) {
      #pragma unroll
      for (int mi = 0; mi < 4; ++mi)
        #pragma unroll
        for (int ni = 0; ni < 4; ++ni) {
          int colb = wn * 64 + ni * 16 + lr;
          #pragma unroll
          for (int rr = 0; rr < 4; ++rr) {
            int row = mi * 16 + lq * 4 + rr;
            int scol = colb ^ (((row >> 2) & 1) << 4);
            Cf[row * 128 + scol] = acc[mi][ni][rr];
          }
        }
    }
    __syncthreads();
    #pragma unroll
    for (int i = 0; i < 8; ++i) {
      int id = i * 256 + t;
      int row = id >> 5, c4 = id & 31;
      int scol = (c4 * 4) ^ (((row >> 2) & 1) << 4);
      float4 v = *(const float4*)(Cf + row * 128 + scol);
      *(float4*)(Cout + (size_t)(m0 + p * 64 + row) * N + n0 + c4 * 4) = v;
    }
  }
}

// -------- flash attention (R18 config, LOCKED): in-register P, 32KB LDS --------
__global__ __launch_bounds__(256) void attn_fwd(const u16* __restrict__ Qp,
                                                const u16* __restrict__ Kp,
                                                const u16* __restrict__ Vt,
                                                const int* __restrict__ cu,
                                                u16* __restrict__ Obf) {
  __shared__ u16 K_lds[64 * 128];    // [kv][d], chunk-swizzled (16 KiB)
  __shared__ u16 VT_lds[128 * 64];   // [d][kv], chunk-swizzled (16 KiB)

  const int t = threadIdx.x;
  const int l = t & 63;
  const int lr = l & 15;
  const int lq = l >> 4;
  const int w = t >> 6;

  const int nwg = gridDim.x;
  const int qc = nwg >> 3, rc = nwg & 7;
  const int xcd = blockIdx.x & 7, rest = blockIdx.x >> 3;
  const int wgid = (xcd < rc ? xcd * (qc + 1) : rc * (qc + 1) + (xcd - rc) * qc) + rest;
  const int h = wgid / (S_LEN / 64);
  const int q0 = (wgid % (S_LEN / 64)) * 64;

  int cs = 0, ce = S_LEN;
  #pragma unroll
  for (int b = 0; b < 4; ++b) {
    int lo = cu[b], hi = cu[b + 1];
    if (q0 >= lo && q0 < hi) { cs = lo; ce = hi; }
  }

  const int qrow = q0 + w * 16 + lr;
  bf16x8 qf[4];
  const u16* qptr = Qp + ((size_t)h * S_LEN + qrow) * HD + lq * 8;
  #pragma unroll
  for (int ks = 0; ks < 4; ++ks) qf[ks] = *(const bf16x8*)(qptr + ks * 32);

  f32x4 acc_o[8];
  #pragma unroll
  for (int i = 0; i < 8; ++i) acc_o[i] = f32x4{0.f, 0.f, 0.f, 0.f};
  float m_run = -1e30f, l_run = 0.f;   // per-lane: row q = lr

  const int o0 = ((l & 16) << 1) | lr;   // owner lane for pa[0..3]
  const int o1 = o0 + 16;                // owner lane for pa[4..7]
  const int hisel = lq >> 1;             // nf parity select

  for (int kv0 = cs; kv0 < ce; kv0 += 64) {
    __syncthreads();
    {
      const u16* kbase = Kp + ((size_t)h * S_LEN + kv0) * HD;
      #pragma unroll
      for (int r4 = 0; r4 < 4; ++r4) {
        int C = t + r4 * 256;
        int row = C >> 4, ch = C & 15;
        int sch = (ch & 8) | ((ch ^ row) & 7);
        GLL16(kbase + row * HD + sch * 8, K_lds + (size_t)C * 8);
      }
      const u16* vbase = Vt + (size_t)h * HD * S_LEN + kv0;
      #pragma unroll
      for (int r4 = 0; r4 < 4; ++r4) {
        int C = t + r4 * 256;
        int row = C >> 3, ch = C & 7;
        int sch = (ch ^ row) & 7;
        GLL16(vbase + (size_t)row * S_LEN + sch * 8, VT_lds + (size_t)C * 8);
      }
    }
    __syncthreads();

    // S^T = K Q^T : s_acc[nf] reg r holds S[q=lr][k = nf*16 + lq*4 + r]
    f32x4 s_acc[4];
    __builtin_amdgcn_s_setprio(1);
    #pragma unroll
    for (int nf = 0; nf < 4; ++nf) {
      s_acc[nf] = f32x4{0.f, 0.f, 0.f, 0.f};
      int krow = nf * 16 + lr;
      #pragma unroll
      for (int ks = 0; ks < 4; ++ks) {
        int ch = ks * 4 + lq;
        int sch = (ch & 8) | ((ch ^ krow) & 7);
        bf16x8 kf = *(const bf16x8*)(K_lds + krow * 128 + sch * 8);
        s_acc[nf] = __builtin_amdgcn_mfma_f32_16x16x32_bf16(kf, qf[ks], s_acc[nf], 0, 0, 0);
      }
    }
    __builtin_amdgcn_s_setprio(0);

    // in-register row softmax (q = lr), 16 k-values per lane
    float vmax = -1e30f;
    #pragma unroll
    for (int nf = 0; nf < 4; ++nf)
      #pragma unroll
      for (int r = 0; r < 4; ++r) vmax = fmaxf(vmax, s_acc[nf][r]);
    vmax = fmaxf(vmax, __shfl_xor(vmax, 16, 64));
    vmax = fmaxf(vmax, __shfl_xor(vmax, 32, 64));
    float mn = fmaxf(m_run, vmax);
    float alpha = __builtin_amdgcn_exp2f(m_run - mn);
    m_run = mn;
    float pv[4][4], sum = 0.f;
    #pragma unroll
    for (int nf = 0; nf < 4; ++nf)
      #pragma unroll
      for (int r = 0; r < 4; ++r) {
        float e = __builtin_amdgcn_exp2f(s_acc[nf][r] - mn);
        pv[nf][r] = e;
        sum += e;
      }
    sum += __shfl_xor(sum, 16, 64);
    sum += __shfl_xor(sum, 32, 64);
    l_run = l_run * alpha + sum;

    float alphaO[4];
    #pragma unroll
    for (int r = 0; r < 4; ++r) alphaO[r] = __shfl(alpha, lq * 20 + r, 64);
    #pragma unroll
    for (int onf = 0; onf < 8; ++onf)
      #pragma unroll
      for (int r = 0; r < 4; ++r) acc_o[onf][r] *= alphaO[r];

    u32 plo[4], phi[4];
    #pragma unroll
    for (int nf = 0; nf < 4; ++nf) {
      plo[nf] = (u32)f2bf(pv[nf][0]) | ((u32)f2bf(pv[nf][1]) << 16);
      phi[nf] = (u32)f2bf(pv[nf][2]) | ((u32)f2bf(pv[nf][3]) << 16);
    }

    #pragma unroll
    for (int ks = 0; ks < 2; ++ks) {
      u32 a0 = __shfl(plo[ks * 2], o0, 64), b0 = __shfl(plo[ks * 2 + 1], o0, 64);
      u32 a1 = __shfl(phi[ks * 2], o0, 64), b1 = __shfl(phi[ks * 2 + 1], o0, 64);
      u32 a2 = __shfl(plo[ks * 2], o1, 64), b2 = __shfl(plo[ks * 2 + 1], o1, 64);
      u32 a3 = __shfl(phi[ks * 2], o1, 64), b3 = __shfl(phi[ks * 2 + 1], o1, 64);
      u32x4 pau;
      pau[0] = hisel ? b0 : a0;
      pau[1] = hisel ? b1 : a1;
      pau[2] = hisel ? b2 : a2;
      pau[3] = hisel ? b3 : a3;
      bf16x8 pa = __builtin_bit_cast(bf16x8, pau);
      __builtin_amdgcn_s_setprio(1);
      #pragma unroll
      for (int onf = 0; onf < 8; ++onf) {
        int d = onf * 16 + lr;
        int ch = ks * 4 + lq;
        int sch = (ch ^ d) & 7;
        bf16x8 vf = *(const bf16x8*)(VT_lds + d * 64 + sch * 8);
        acc_o[onf] = __builtin_amdgcn_mfma_f32_16x16x32_bf16(pa, vf, acc_o[onf], 0, 0, 0);
      }
      __builtin_amdgcn_s_setprio(0);
    }
  }

  float invO[4];
  #pragma unroll
  for (int r = 0; r < 4; ++r) invO[r] = 1.f / __shfl(l_run, lq * 20 + r, 64);
  #pragma unroll
  for (int r = 0; r < 4; ++r) {
    int srow = q0 + w * 16 + (lq << 2) + r;
    u16* orow = Obf + (size_t)srow * DIM + h * HD + lr;
    #pragma unroll
    for (int onf = 0; onf < 8; ++onf) orow[onf * 16] = f2bf(acc_o[onf][r] * invO[r]);
  }
}

extern "C" void kernel_launch(void* const* d_in, const int* in_sizes, int n_in,
                              void* d_out, int out_size, void* d_ws, size_t ws_size,
                              hipStream_t stream) {
  const float* hidden = (const float*)d_in[0];
  const float* cosb   = (const float*)d_in[1];
  const float* sinb   = (const float*)d_in[2];
  const float* qkv_w  = (const float*)d_in[3];
  const float* qkv_b  = (const float*)d_in[4];
  const float* proj_w = (const float*)d_in[5];
  const int*   cu     = (const int*)d_in[6];

  u16* Hbf   = (u16*)d_ws;
  u16* Wqkv  = Hbf   + (size_t)S_LEN * DIM;
  u16* Wproj = Wqkv  + (size_t)QKV_N * DIM;
  u16* Qp    = Wproj + (size_t)DIM * DIM;
  u16* Kp    = Qp    + (size_t)NH * S_LEN * HD;
  u16* Vt    = Kp    + (size_t)NH * S_LEN * HD;
  u16* Abf   = Hbf;   // reuse: Hbf dead after GEMM1

  cvt_bf16_3<<<2048, 256, 0, stream>>>(hidden, Hbf, S_LEN * DIM / 4,
                                       qkv_w, Wqkv, QKV_N * DIM / 4,
                                       proj_w, Wproj, DIM * DIM / 4);

  gemm_qkvf<<<(S_LEN / 256) * (QKV_N / 256), 512, 0, stream>>>(
      Hbf, Wqkv, qkv_b, cosb, sinb, Qp, Kp, Vt, S_LEN, QKV_N, DIM);

  attn_fwd<<<(S_LEN / 64) * NH, 256, 0, stream>>>(Qp, Kp, Vt, cu, Abf);

  gemm_proj<<<(S_LEN / 128) * (DIM / 128), 256, 0, stream>>>(
      Abf, Wproj, (float*)d_out, S_LEN, DIM, DIM);
}

// Round 21
// 139.226 us; speedup vs baseline: 1.0683x; 1.0683x over previous
//
#include <hip/hip_runtime.h>
#include <stdint.h>

#define S_LEN 3072
#define DIM   1536
#define NH    12
#define HD    128
#define QKV_N 4608   // 3*DIM

typedef unsigned short u16;
typedef unsigned int   u32;
typedef __bf16 bf16x8 __attribute__((ext_vector_type(8)));
typedef float  f32x4  __attribute__((ext_vector_type(4)));
typedef u16    u16x8  __attribute__((ext_vector_type(8)));
typedef u16    u16x4  __attribute__((ext_vector_type(4)));
typedef u32    u32x4  __attribute__((ext_vector_type(4)));

#define AS1 __attribute__((address_space(1)))
#define AS3 __attribute__((address_space(3)))
#define GLL16(g, l) __builtin_amdgcn_global_load_lds((AS1 void*)(g), (AS3 void*)(l), 16, 0, 0)

__device__ __forceinline__ u16 f2bf(float f) {
  unsigned u = __float_as_uint(f);
  u = (u + 0x7fffu + ((u >> 16) & 1u)) >> 16;   // RNE
  return (u16)u;
}
__device__ __forceinline__ float bf2f(u16 b) {
  return __uint_as_float(((unsigned)b) << 16);
}

// ---------------- fused fp32 -> bf16 convert (3 tensors, one launch) ----------
__global__ __launch_bounds__(256) void cvt_bf16_3(const float* __restrict__ in0, u16* __restrict__ out0, int n0,
                                                  const float* __restrict__ in1, u16* __restrict__ out1, int n1,
                                                  const float* __restrict__ in2, u16* __restrict__ out2, int n2) {
  int total = n0 + n1 + n2;
  int stride = gridDim.x * blockDim.x;
  for (int i = blockIdx.x * blockDim.x + threadIdx.x; i < total; i += stride) {
    const float* src; u16* dst; int j;
    if (i < n0)           { src = in0; dst = out0; j = i; }
    else if (i < n0 + n1) { src = in1; dst = out1; j = i - n0; }
    else                  { src = in2; dst = out2; j = i - n0 - n1; }
    float4 v = ((const float4*)src)[j];
    ushort4 o;
    o.x = f2bf(v.x); o.y = f2bf(v.y); o.z = f2bf(v.z); o.w = f2bf(v.w);
    ((ushort4*)dst)[j] = o;
  }
}

// ======= GEMM1 (QKV) 256x256 8-phase + FUSED epilogue: rope q/k, transpose v ===
// (frozen: R11 config — BK=64, 128KB LDS; 5 schedule variants tested, this wins)
__global__ __launch_bounds__(512, 2) void gemm_qkvf(const u16* __restrict__ A,
                                                    const u16* __restrict__ B,
                                                    const float* __restrict__ bias,
                                                    const float* __restrict__ cosb,
                                                    const float* __restrict__ sinb,
                                                    u16* __restrict__ Qp,
                                                    u16* __restrict__ Kp,
                                                    u16* __restrict__ Vt,
                                                    int M, int N, int K) {
  __shared__ __attribute__((aligned(16))) u16 lds[8 * 8192];  // 128 KiB

  const int t = threadIdx.x;
  const int l = t & 63;
  const int w = t >> 6;          // 0..7
  const int wm = w >> 2;         // 0..1  (128 rows)
  const int wn = w & 3;          // 0..3  (64 cols)
  const int lr = l & 15;
  const int lc = l >> 4;

  const int nbx = N >> 8;
  const int nwg = gridDim.x;
  const int q = nwg >> 3, r = nwg & 7;
  const int xcd = blockIdx.x & 7, rest = blockIdx.x >> 3;
  const int wgid = (xcd < r ? xcd * (q + 1) : r * (q + 1) + (xcd - r) * q) + rest;
  const int m0 = (wgid / nbx) * 256;
  const int n0 = (wgid % nbx) * 256;

  const int nk = K >> 6;

  f32x4 acc[8][4];
  #pragma unroll
  for (int i = 0; i < 8; ++i)
    #pragma unroll
    for (int j = 0; j < 4; ++j) acc[i][j] = f32x4{0.f, 0.f, 0.f, 0.f};

  auto frag2 = [&](const u16* region, int row, int ch) {
    int L = row >> 1;
    int slot = ((ch + ((row & 1) << 2)) ^ L) & 7;
    return *(const bf16x8*)(region + L * 64 + slot * 8);
  };
  auto stage_half = [&](int buf, int ks, int ab, int kt) {
    const u16* base = ab ? B : A;
    const int x0 = ab ? n0 : m0;
    u16* dst = lds + (((buf << 2) | (ks << 1) | ab) * 8192);
    #pragma unroll
    for (int i = 0; i < 2; ++i) {
      int C = t + i * 512;
      int L = C >> 3, s = C & 7;
      int u = s ^ (L & 7);
      int row = 2 * L + (u >> 2), ch = u & 3;
      const u16* src = base + (size_t)(x0 + row) * K + kt * 64 + ks * 32 + ch * 8;
      GLL16(src, dst + C * 8);
    }
  };

  stage_half(0, 0, 0, 0); stage_half(0, 0, 1, 0);
  stage_half(0, 1, 0, 0); stage_half(0, 1, 1, 0);
  if (nk > 1) { stage_half(1, 0, 0, 1); stage_half(1, 0, 1, 1); }
  asm volatile("s_waitcnt vmcnt(4)" ::: "memory");
  __builtin_amdgcn_s_barrier();

  for (int kt = 0; kt < nk; ++kt) {
    const int buf = kt & 1, nbuf = buf ^ 1;
    const bool st1 = (kt + 1 < nk);
    const bool st2 = (kt + 2 < nk);

    const u16* A0 = lds + (((buf << 2) | 0) * 8192);
    const u16* B0 = lds + (((buf << 2) | 1) * 8192);
    const u16* A1 = lds + (((buf << 2) | 2) * 8192);
    const u16* B1 = lds + (((buf << 2) | 3) * 8192);

    bf16x8 bfrag[4], afr[4];

    // ---- ph0 ----
    #pragma unroll
    for (int ni = 0; ni < 4; ++ni) bfrag[ni] = frag2(B0, wn * 64 + ni * 16 + lr, lc);
    #pragma unroll
    for (int mi = 0; mi < 4; ++mi) afr[mi] = frag2(A0, wm * 128 + mi * 16 + lr, lc);
    if (st1) stage_half(nbuf, 1, 0, kt + 1);
    __builtin_amdgcn_s_barrier();
    __builtin_amdgcn_s_setprio(1);
    #pragma unroll
    for (int mi = 0; mi < 4; ++mi)
      #pragma unroll
      for (int ni = 0; ni < 4; ++ni)
        acc[mi][ni] = __builtin_amdgcn_mfma_f32_16x16x32_bf16(afr[mi], bfrag[ni],
                                                              acc[mi][ni], 0, 0, 0);
    __builtin_amdgcn_s_setprio(0);
    __builtin_amdgcn_s_barrier();

    // ---- ph1 ----
    #pragma unroll
    for (int mi = 0; mi < 4; ++mi) afr[mi] = frag2(A0, wm * 128 + 64 + mi * 16 + lr, lc);
    if (st1) stage_half(nbuf, 1, 1, kt + 1);
    __builtin_amdgcn_s_barrier();
    __builtin_amdgcn_s_setprio(1);
    #pragma unroll
    for (int mi = 0; mi < 4; ++mi)
      #pragma unroll
      for (int ni = 0; ni < 4; ++ni)
        acc[4 + mi][ni] = __builtin_amdgcn_mfma_f32_16x16x32_bf16(afr[mi], bfrag[ni],
                                                                  acc[4 + mi][ni], 0, 0, 0);
    __builtin_amdgcn_s_setprio(0);
    __builtin_amdgcn_s_barrier();

    // ---- ph2 ----
    #pragma unroll
    for (int ni = 0; ni < 4; ++ni) bfrag[ni] = frag2(B1, wn * 64 + ni * 16 + lr, lc);
    #pragma unroll
    for (int mi = 0; mi < 4; ++mi) afr[mi] = frag2(A1, wm * 128 + mi * 16 + lr, lc);
    if (st2) stage_half(buf, 0, 0, kt + 2);
    __builtin_amdgcn_s_barrier();
    __builtin_amdgcn_s_setprio(1);
    #pragma unroll
    for (int mi = 0; mi < 4; ++mi)
      #pragma unroll
      for (int ni = 0; ni < 4; ++ni)
        acc[mi][ni] = __builtin_amdgcn_mfma_f32_16x16x32_bf16(afr[mi], bfrag[ni],
                                                              acc[mi][ni], 0, 0, 0);
    __builtin_amdgcn_s_setprio(0);
    __builtin_amdgcn_s_barrier();

    // ---- ph3 ----
    #pragma unroll
    for (int mi = 0; mi < 4; ++mi) afr[mi] = frag2(A1, wm * 128 + 64 + mi * 16 + lr, lc);
    if (st2) {
      stage_half(buf, 0, 1, kt + 2);
      asm volatile("s_waitcnt vmcnt(4)" ::: "memory");
    } else if (st1) {
      asm volatile("s_waitcnt vmcnt(0)" ::: "memory");
    }
    __builtin_amdgcn_s_barrier();
    __builtin_amdgcn_s_setprio(1);
    #pragma unroll
    for (int mi = 0; mi < 4; ++mi)
      #pragma unroll
      for (int ni = 0; ni < 4; ++ni)
        acc[4 + mi][ni] = __builtin_amdgcn_mfma_f32_16x16x32_bf16(afr[mi], bfrag[ni],
                                                                  acc[4 + mi][ni], 0, 0, 0);
    __builtin_amdgcn_s_setprio(0);
    __builtin_amdgcn_s_barrier();
  }

  // ---- fused epilogue ----
  const int sec = n0 / DIM;           // 0=q, 1=k, 2=v
  const int h0 = (n0 % DIM) >> 7;

  {
    float bv[4];
    #pragma unroll
    for (int ni = 0; ni < 4; ++ni)
      bv[ni] = bias[n0 + wn * 64 + ni * 16 + lr];
    #pragma unroll
    for (int mi = 0; mi < 8; ++mi) {
      int rbase = wm * 128 + mi * 16 + lc * 4;
      int s4 = (rbase >> 3) & 15;
      #pragma unroll
      for (int ni = 0; ni < 4; ++ni) {
        int scol = (wn * 64 + ni * 16 + lr) ^ (s4 << 4);
        #pragma unroll
        for (int rr = 0; rr < 4; ++rr)
          lds[(rbase + rr) * 256 + scol] = f2bf(acc[mi][ni][rr] + bv[ni]);
      }
    }
  }
  __syncthreads();

  if (sec < 2) {
    u16* dst = sec ? Kp : Qp;
    const float sc = sec ? 1.f : (0.08838834764831845f * 1.4426950408889634f);
    #pragma unroll
    for (int i = 0; i < 16; ++i) {
      int id = i * 512 + t;
      int row = id >> 5, c16 = id & 31;
      int srow = m0 + row;
      int s4 = (row >> 3) & 15;
      int c8 = c16 * 8;
      u16x8 x  = *(const u16x8*)(lds + row * 256 + (c8 ^ (s4 << 4)));
      u16x8 xp = *(const u16x8*)(lds + row * 256 + ((c8 ^ 64) ^ (s4 << 4)));
      int h = h0 + (c8 >> 7);
      int d = c8 & 127;
      float cs[8], sn[8];
      *(float4*)(cs)     = *(const float4*)(cosb + (size_t)srow * HD + d);
      *(float4*)(cs + 4) = *(const float4*)(cosb + (size_t)srow * HD + d + 4);
      *(float4*)(sn)     = *(const float4*)(sinb + (size_t)srow * HD + d);
      *(float4*)(sn + 4) = *(const float4*)(sinb + (size_t)srow * HD + d + 4);
      const float sg = (d & 64) ? 1.f : -1.f;
      u16x8 o;
      #pragma unroll
      for (int j = 0; j < 8; ++j)
        o[j] = f2bf((bf2f(x[j]) * cs[j] + sg * bf2f(xp[j]) * sn[j]) * sc);
      *(u16x8*)(dst + ((size_t)h * S_LEN + srow) * HD + d) = o;
    }
  } else {
    #pragma unroll
    for (int i = 0; i < 16; ++i) {
      int id = i * 512 + t;
      int col = (((id >> 6) & 31) << 3) | ((id >> 3) & 7);
      int sch = (id & 7) | (((id >> 11) & 3) << 3);
      int h = h0 + (col >> 7), d = col & 127;
      int scol = col ^ ((sch & 15) << 4);
      u16x8 v;
      #pragma unroll
      for (int e = 0; e < 8; ++e)
        v[e] = lds[(sch * 8 + e) * 256 + scol];
      *(u16x8*)(Vt + ((size_t)h * HD + d) * S_LEN + m0 + sch * 8) = v;
    }
  }
}

// --------- GEMM2 (proj): 128x128, LDS-staged fp32 epilogue + XCD chunking ------
__device__ __forceinline__ bf16x8 lds_frag(const u16* base, int row, int ch) {
  return *(const bf16x8*)(base + row * 64 + ((ch ^ row) & 7) * 8);
}

__global__ __launch_bounds__(256) void gemm_proj(const u16* __restrict__ A,
                                                 const u16* __restrict__ B,
                                                 float* __restrict__ Cout,
                                                 int M, int N, int K) {
  __shared__ __attribute__((aligned(16))) u16 smem[2 * 128 * 64];  // 32 KiB
  u16* Asm = smem;
  u16* Bsm = smem + 128 * 64;

  const int t = threadIdx.x;
  const int l = t & 63;
  const int w = t >> 6;
  const int wm = w >> 1, wn = w & 1;
  const int lr = l & 15;
  const int lq = l >> 4;

  const int nbx = N >> 7;   // 12
  const int nwg = gridDim.x;
  const int qc = nwg >> 3, rc = nwg & 7;
  const int xcd = blockIdx.x & 7, rest = blockIdx.x >> 3;
  const int wgid = (xcd < rc ? xcd * (qc + 1) : rc * (qc + 1) + (xcd - rc) * qc) + rest;
  const int m0 = (wgid / nbx) * 128;
  const int n0 = (wgid % nbx) * 128;

  f32x4 acc[4][4];
  #pragma unroll
  for (int i = 0; i < 4; ++i)
    #pragma unroll
    for (int j = 0; j < 4; ++j) acc[i][j] = f32x4{0.f, 0.f, 0.f, 0.f};

  for (int k0 = 0; k0 < K; k0 += 64) {
    __syncthreads();
    #pragma unroll
    for (int r4 = 0; r4 < 4; ++r4) {
      int C = t + r4 * 256;
      int row = C >> 3, ch = C & 7;
      int sch = (ch ^ row) & 7;
      GLL16(A + (size_t)(m0 + row) * K + k0 + sch * 8, Asm + (size_t)C * 8);
      GLL16(B + (size_t)(n0 + row) * K + k0 + sch * 8, Bsm + (size_t)C * 8);
    }
    __syncthreads();
    #pragma unroll
    for (int ks = 0; ks < 2; ++ks) {
      bf16x8 af[4], bfr[4];
      #pragma unroll
      for (int mi = 0; mi < 4; ++mi)
        af[mi] = lds_frag(Asm, wm * 64 + mi * 16 + lr, ks * 4 + lq);
      #pragma unroll
      for (int ni = 0; ni < 4; ++ni)
        bfr[ni] = lds_frag(Bsm, wn * 64 + ni * 16 + lr, ks * 4 + lq);
      #pragma unroll
      for (int mi = 0; mi < 4; ++mi)
        #pragma unroll
        for (int ni = 0; ni < 4; ++ni)
          acc[mi][ni] = __builtin_amdgcn_mfma_f32_16x16x32_bf16(af[mi], bfr[ni],
                                                                acc[mi][ni], 0, 0, 0);
    }
  }

  float* Cf = (float*)smem;
  #pragma unroll
  for (int p = 0; p < 2; ++p) {
    __syncthreads();
    if (wm == p) {
      #pragma unroll
      for (int mi = 0; mi < 4; ++mi)
        #pragma unroll
        for (int ni = 0; ni < 4; ++ni) {
          int colb = wn * 64 + ni * 16 + lr;
          #pragma unroll
          for (int rr = 0; rr < 4; ++rr) {
            int row = mi * 16 + lq * 4 + rr;
            int scol = colb ^ (((row >> 2) & 1) << 4);
            Cf[row * 128 + scol] = acc[mi][ni][rr];
          }
        }
    }
    __syncthreads();
    #pragma unroll
    for (int i = 0; i < 8; ++i) {
      int id = i * 256 + t;
      int row = id >> 5, c4 = id & 31;
      int scol = (c4 * 4) ^ (((row >> 2) & 1) << 4);
      float4 v = *(const float4*)(Cf + row * 128 + scol);
      *(float4*)(Cout + (size_t)(m0 + p * 64 + row) * N + n0 + c4 * 4) = v;
    }
  }
}

// -------- flash attention (R18 config, LOCKED): in-register P, 32KB LDS --------
__global__ __launch_bounds__(256) void attn_fwd(const u16* __restrict__ Qp,
                                                const u16* __restrict__ Kp,
                                                const u16* __restrict__ Vt,
                                                const int* __restrict__ cu,
                                                u16* __restrict__ Obf) {
  __shared__ u16 K_lds[64 * 128];    // [kv][d], chunk-swizzled (16 KiB)
  __shared__ u16 VT_lds[128 * 64];   // [d][kv], chunk-swizzled (16 KiB)

  const int t = threadIdx.x;
  const int l = t & 63;
  const int lr = l & 15;
  const int lq = l >> 4;
  const int w = t >> 6;

  const int nwg = gridDim.x;
  const int qc = nwg >> 3, rc = nwg & 7;
  const int xcd = blockIdx.x & 7, rest = blockIdx.x >> 3;
  const int wgid = (xcd < rc ? xcd * (qc + 1) : rc * (qc + 1) + (xcd - rc) * qc) + rest;
  const int h = wgid / (S_LEN / 64);
  const int q0 = (wgid % (S_LEN / 64)) * 64;

  int cs = 0, ce = S_LEN;
  #pragma unroll
  for (int b = 0; b < 4; ++b) {
    int lo = cu[b], hi = cu[b + 1];
    if (q0 >= lo && q0 < hi) { cs = lo; ce = hi; }
  }

  const int qrow = q0 + w * 16 + lr;
  bf16x8 qf[4];
  const u16* qptr = Qp + ((size_t)h * S_LEN + qrow) * HD + lq * 8;
  #pragma unroll
  for (int ks = 0; ks < 4; ++ks) qf[ks] = *(const bf16x8*)(qptr + ks * 32);

  f32x4 acc_o[8];
  #pragma unroll
  for (int i = 0; i < 8; ++i) acc_o[i] = f32x4{0.f, 0.f, 0.f, 0.f};
  float m_run = -1e30f, l_run = 0.f;   // per-lane: row q = lr

  const int o0 = ((l & 16) << 1) | lr;   // owner lane for pa[0..3]
  const int o1 = o0 + 16;                // owner lane for pa[4..7]
  const int hisel = lq >> 1;             // nf parity select

  for (int kv0 = cs; kv0 < ce; kv0 += 64) {
    __syncthreads();
    {
      const u16* kbase = Kp + ((size_t)h * S_LEN + kv0) * HD;
      #pragma unroll
      for (int r4 = 0; r4 < 4; ++r4) {
        int C = t + r4 * 256;
        int row = C >> 4, ch = C & 15;
        int sch = (ch & 8) | ((ch ^ row) & 7);
        GLL16(kbase + row * HD + sch * 8, K_lds + (size_t)C * 8);
      }
      const u16* vbase = Vt + (size_t)h * HD * S_LEN + kv0;
      #pragma unroll
      for (int r4 = 0; r4 < 4; ++r4) {
        int C = t + r4 * 256;
        int row = C >> 3, ch = C & 7;
        int sch = (ch ^ row) & 7;
        GLL16(vbase + (size_t)row * S_LEN + sch * 8, VT_lds + (size_t)C * 8);
      }
    }
    __syncthreads();

    // S^T = K Q^T : s_acc[nf] reg r holds S[q=lr][k = nf*16 + lq*4 + r]
    f32x4 s_acc[4];
    __builtin_amdgcn_s_setprio(1);
    #pragma unroll
    for (int nf = 0; nf < 4; ++nf) {
      s_acc[nf] = f32x4{0.f, 0.f, 0.f, 0.f};
      int krow = nf * 16 + lr;
      #pragma unroll
      for (int ks = 0; ks < 4; ++ks) {
        int ch = ks * 4 + lq;
        int sch = (ch & 8) | ((ch ^ krow) & 7);
        bf16x8 kf = *(const bf16x8*)(K_lds + krow * 128 + sch * 8);
        s_acc[nf] = __builtin_amdgcn_mfma_f32_16x16x32_bf16(kf, qf[ks], s_acc[nf], 0, 0, 0);
      }
    }
    __builtin_amdgcn_s_setprio(0);

    // in-register row softmax (q = lr), 16 k-values per lane
    float vmax = -1e30f;
    #pragma unroll
    for (int nf = 0; nf < 4; ++nf)
      #pragma unroll
      for (int r = 0; r < 4; ++r) vmax = fmaxf(vmax, s_acc[nf][r]);
    vmax = fmaxf(vmax, __shfl_xor(vmax, 16, 64));
    vmax = fmaxf(vmax, __shfl_xor(vmax, 32, 64));
    float mn = fmaxf(m_run, vmax);
    float alpha = __builtin_amdgcn_exp2f(m_run - mn);
    m_run = mn;
    float pv[4][4], sum = 0.f;
    #pragma unroll
    for (int nf = 0; nf < 4; ++nf)
      #pragma unroll
      for (int r = 0; r < 4; ++r) {
        float e = __builtin_amdgcn_exp2f(s_acc[nf][r] - mn);
        pv[nf][r] = e;
        sum += e;
      }
    sum += __shfl_xor(sum, 16, 64);
    sum += __shfl_xor(sum, 32, 64);
    l_run = l_run * alpha + sum;

    float alphaO[4];
    #pragma unroll
    for (int r = 0; r < 4; ++r) alphaO[r] = __shfl(alpha, lq * 20 + r, 64);
    #pragma unroll
    for (int onf = 0; onf < 8; ++onf)
      #pragma unroll
      for (int r = 0; r < 4; ++r) acc_o[onf][r] *= alphaO[r];

    u32 plo[4], phi[4];
    #pragma unroll
    for (int nf = 0; nf < 4; ++nf) {
      plo[nf] = (u32)f2bf(pv[nf][0]) | ((u32)f2bf(pv[nf][1]) << 16);
      phi[nf] = (u32)f2bf(pv[nf][2]) | ((u32)f2bf(pv[nf][3]) << 16);
    }

    #pragma unroll
    for (int ks = 0; ks < 2; ++ks) {
      u32 a0 = __shfl(plo[ks * 2], o0, 64), b0 = __shfl(plo[ks * 2 + 1], o0, 64);
      u32 a1 = __shfl(phi[ks * 2], o0, 64), b1 = __shfl(phi[ks * 2 + 1], o0, 64);
      u32 a2 = __shfl(plo[ks * 2], o1, 64), b2 = __shfl(plo[ks * 2 + 1], o1, 64);
      u32 a3 = __shfl(phi[ks * 2], o1, 64), b3 = __shfl(phi[ks * 2 + 1], o1, 64);
      u32x4 pau;
      pau[0] = hisel ? b0 : a0;
      pau[1] = hisel ? b1 : a1;
      pau[2] = hisel ? b2 : a2;
      pau[3] = hisel ? b3 : a3;
      bf16x8 pa = __builtin_bit_cast(bf16x8, pau);
      __builtin_amdgcn_s_setprio(1);
      #pragma unroll
      for (int onf = 0; onf < 8; ++onf) {
        int d = onf * 16 + lr;
        int ch = ks * 4 + lq;
        int sch = (ch ^ d) & 7;
        bf16x8 vf = *(const bf16x8*)(VT_lds + d * 64 + sch * 8);
        acc_o[onf] = __builtin_amdgcn_mfma_f32_16x16x32_bf16(pa, vf, acc_o[onf], 0, 0, 0);
      }
      __builtin_amdgcn_s_setprio(0);
    }
  }

  float invO[4];
  #pragma unroll
  for (int r = 0; r < 4; ++r) invO[r] = 1.f / __shfl(l_run, lq * 20 + r, 64);
  #pragma unroll
  for (int r = 0; r < 4; ++r) {
    int srow = q0 + w * 16 + (lq << 2) + r;
    u16* orow = Obf + (size_t)srow * DIM + h * HD + lr;
    #pragma unroll
    for (int onf = 0; onf < 8; ++onf) orow[onf * 16] = f2bf(acc_o[onf][r] * invO[r]);
  }
}

extern "C" void kernel_launch(void* const* d_in, const int* in_sizes, int n_in,
                              void* d_out, int out_size, void* d_ws, size_t ws_size,
                              hipStream_t stream) {
  const float* hidden = (const float*)d_in[0];
  const float* cosb   = (const float*)d_in[1];
  const float* sinb   = (const float*)d_in[2];
  const float* qkv_w  = (const float*)d_in[3];
  const float* qkv_b  = (const float*)d_in[4];
  const float* proj_w = (const float*)d_in[5];
  const int*   cu     = (const int*)d_in[6];

  u16* Hbf   = (u16*)d_ws;
  u16* Wqkv  = Hbf   + (size_t)S_LEN * DIM;
  u16* Wproj = Wqkv  + (size_t)QKV_N * DIM;
  u16* Qp    = Wproj + (size_t)DIM * DIM;
  u16* Kp    = Qp    + (size_t)NH * S_LEN * HD;
  u16* Vt    = Kp    + (size_t)NH * S_LEN * HD;
  u16* Abf   = Hbf;   // reuse: Hbf dead after GEMM1

  cvt_bf16_3<<<2048, 256, 0, stream>>>(hidden, Hbf, S_LEN * DIM / 4,
                                       qkv_w, Wqkv, QKV_N * DIM / 4,
                                       proj_w, Wproj, DIM * DIM / 4);

  gemm_qkvf<<<(S_LEN / 256) * (QKV_N / 256), 512, 0, stream>>>(
      Hbf, Wqkv, qkv_b, cosb, sinb, Qp, Kp, Vt, S_LEN, QKV_N, DIM);

  attn_fwd<<<(S_LEN / 64) * NH, 256, 0, stream>>>(Qp, Kp, Vt, cu, Abf);

  gemm_proj<<<(S_LEN / 128) * (DIM / 128), 256, 0, stream>>>(
      Abf, Wproj, (float*)d_out, S_LEN, DIM, DIM);
}